// Round 7
// baseline (612.694 us; speedup 1.0000x reference)
//
#include <hip/hip_runtime.h>

// DeepSNNController: 3-layer LIF SNN, T=100, B=4096, 9 -> 96 -> 96 -> 48.
//
// R15 "triple-split" = R13's BPW=4 LDS economics at R14's 3-waves/SIMD
// occupancy. Key identity: a weight ds_read_b128 feeds 4*BPW MACs, and
// neuron-splitting CONSERVES total weight-read instructions (each still
// feeds 1024 MACs). So: 3 waves share each 4-batch group, splitting neurons:
//   role h (0..2): L1 neurons [32h,32h+32) (2 dots/lane),
//                  L2 s in {2h, 2h+1}, L3 s = h        -- perfectly balanced.
// Weight traffic/CU/t: 216 b128 (= R13) instead of R14's 432; occupancy
// 12 waves/CU (= R14 x1.5). Spikes are now cross-wave -> 2 barriers/t, but
// as RAW s_barrier with lgkmcnt(0)-only fences (no vmcnt drain!) so the
// x(t+1) register-prefetch stays in flight across barriers. Block = 6 waves
// (2 groups, 384 thr), grid 512 = 2 blocks/CU; balanced phases keep the
// barrier convoy small.
//
// Exactness (absmax must stay 0): identical P7 arithmetic as R9-R14 (all
// passed absmax=0): mod-4 k-split, lane r owns residue r (k=4j+r), fmaf
// chain ascending j; combine (c0+c1)+(c2+c3) via 2 quad-perm DPP
// exchange-adds (IEEE fadd bitwise-commutative -> identical bits in all
// lanes). K=9 L1: tail-first r0=(q8+q0)+q4 verbatim. Products exact
// (spikes in {0,1}); LIF pinned: mn = ((0.92*mp)+(dot+b)) - reset.
// Ownership is a pure re-partition: every (neuron,batch) LIF chain lives in
// exactly one lane with the same op sequence.
//
// Hazards (2 raw barriers/t):
//   BAR1 (post-L1): s1p writes (all 3 roles) visible to L2 readers.
//   BAR2 (post-L2): s2p writes visible to L3 readers.
//   L1(t+1) writes s1p only after BAR2(t); L2(t) reads drained at BAR2's
//   lgkmcnt(0). L2(t+1) writes s2p only after BAR1(t+1); each wave reaches
//   BAR1(t+1) only after its L3(t) reads drained (lgkmcnt(0) in BAR1). OK.
//   Global out-stores are never read back; x-prefetch loads complete via
//   compiler-inserted vmcnt before their register use in L1(t+1).
//
// Mapping spot-checks (hand-verified, same formats as R13):
//   W2L cell (c=s*6+jq, l)[jj] = W2[16s+q][16jq+4jj+r]; role h reads
//     c = (2h+si)*6+jq -> covers s=2h,2h+1; j=4jq+jj ascending  OK.
//   spike(n=17,b=2): L1 writer role h=0 (17<32), lane l15=1,i=1,bL=2:
//     byte ((17&3)*24+(17>>2))*4+2 = 114; L2 reader r=1,jq=1: dword
//     [g][1][4].byte2 = (24+4)*4+2 = 114  OK.

constexpr int T_STEPS = 100;
constexpr int BATCH   = 4096;
constexpr int D_INP   = 9;
constexpr int H       = 96;
constexpr int H3      = 48;
constexpr int NGROUP  = 2;              // 4-batch groups per block
constexpr int NB      = NGROUP * 4;     // 8 batches per block
constexpr int BLOCK   = NGROUP * 3 * 64;// 384 threads = 6 waves
constexpr int NBLK    = BATCH / NB;     // 512 blocks = 2 per CU

__device__ __forceinline__ float lif_step(float sum, float bias, float& m) {
    const float cur   = __fadd_rn(sum, bias);
    const float mp    = m;
    const float reset = (mp > 1.0f) ? 1.0f : 0.0f;
    const float mn    = __fsub_rn(__fadd_rn(__fmul_rn(0.92f, mp), cur), reset);
    m = mn;
    return mn;
}

#if defined(__has_builtin)
#if __has_builtin(__builtin_amdgcn_mov_dpp)
#define SNN_HAS_DPP 1
#endif
#endif

// Quad exchange-and-add. CTRL=0xB1: quad_perm [1,0,3,2] (xor 1);
// CTRL=0x4E: quad_perm [2,3,0,1] (xor 2).
template <int CTRL>
__device__ __forceinline__ float xadd(float c) {
#ifdef SNN_HAS_DPP
    const int o = __builtin_amdgcn_mov_dpp(__float_as_int(c), CTRL, 0xF, 0xF, false);
    return __fadd_rn(c, __int_as_float(o));
#else
    return __fadd_rn(c, __shfl_xor(c, (CTRL == 0xB1) ? 1 : 2, 64));
#endif
}

// lanes r=0..3 hold P7 residue partials c_r; returns (c0+c1)+(c2+c3) in ALL lanes.
__device__ __forceinline__ float quad_red(float c) {
    return xadd<0x4E>(xadd<0xB1>(c));
}

#define UNPACK4(dw, row)                                                      \
    sf[row][0] = (float)( (dw)        & 255u);                                \
    sf[row][1] = (float)(((dw) >> 8)  & 255u);                                \
    sf[row][2] = (float)(((dw) >> 16) & 255u);                                \
    sf[row][3] = (float)( (dw) >> 24);

// 16 fmas: weight component jj pairs with spike row jj (j = 4*jq+jj ascending).
#define FMA16(accv, wv)                                                       \
    accv[0] = fmaf(wv.x, sf[0][0], accv[0]);                                  \
    accv[1] = fmaf(wv.x, sf[0][1], accv[1]);                                  \
    accv[2] = fmaf(wv.x, sf[0][2], accv[2]);                                  \
    accv[3] = fmaf(wv.x, sf[0][3], accv[3]);                                  \
    accv[0] = fmaf(wv.y, sf[1][0], accv[0]);                                  \
    accv[1] = fmaf(wv.y, sf[1][1], accv[1]);                                  \
    accv[2] = fmaf(wv.y, sf[1][2], accv[2]);                                  \
    accv[3] = fmaf(wv.y, sf[1][3], accv[3]);                                  \
    accv[0] = fmaf(wv.z, sf[2][0], accv[0]);                                  \
    accv[1] = fmaf(wv.z, sf[2][1], accv[1]);                                  \
    accv[2] = fmaf(wv.z, sf[2][2], accv[2]);                                  \
    accv[3] = fmaf(wv.z, sf[2][3], accv[3]);                                  \
    accv[0] = fmaf(wv.w, sf[3][0], accv[0]);                                  \
    accv[1] = fmaf(wv.w, sf[3][1], accv[1]);                                  \
    accv[2] = fmaf(wv.w, sf[3][2], accv[2]);                                  \
    accv[3] = fmaf(wv.w, sf[3][3], accv[3]);

// Raw block barrier: LDS drained, but VMEM (x-prefetch, out-stores) NOT
// drained -- that's the point. "memory" asm fences pin compiler ordering.
#define BLOCK_SYNC()                                                          \
    do {                                                                      \
        asm volatile("s_waitcnt lgkmcnt(0)" ::: "memory");                    \
        __builtin_amdgcn_s_barrier();                                         \
        asm volatile("" ::: "memory");                                        \
    } while (0)

__global__ __launch_bounds__(BLOCK, 3)
void snn_tri(const float* __restrict__ x,
             const float* __restrict__ W1g, const float* __restrict__ b1g,
             const float* __restrict__ W2g, const float* __restrict__ b2g,
             const float* __restrict__ W3g, const float* __restrict__ b3g,
             float* __restrict__ out)
{
    // Chunk-major weights (R12/R13-measured conflict-free): cell (c,l)=16B.
    __shared__ __align__(16) float    W2L[36 * 64 * 4];   // 36864 B
    __shared__ __align__(16) float    W3L[18 * 64 * 4];   // 18432 B
    __shared__ __align__(16) float    W1L[96 * 12];       //  4608 B
    // Batch-packed spikes per group: dword (g,r,j) bytes = batches g*4+0..3.
    __shared__ __align__(16) unsigned s1p[NGROUP][4][24]; //   768 B
    __shared__ __align__(16) unsigned s2p[NGROUP][4][24]; //   768 B
    // total 61,440 B -> 2 blocks/CU (grid 512) = 12 waves/CU = 3/SIMD.

    const int tid = threadIdx.x;
    const int w   = tid >> 6;       // wave 0..5
    const int l   = tid & 63;       // lane
    const int q   = l >> 2;         // quad 0..15
    const int r   = l & 3;          // residue lane
    const int l15 = l & 15;
    const int bL  = l >> 4;         // L1 batch 0..3
    const int g   = w / 3;          // batch group 0..1
    const int h   = w - 3 * g;      // neuron role 0..2
    const int bgp = blockIdx.x * NB + g * 4;   // group's batch base

    // ---- one-time weight staging (scattered; L2-cached) ----
    for (int idx = tid; idx < 36 * 64; idx += BLOCK) {
        const int c = idx >> 6, ll = idx & 63;
        const int s = c / 6, jq = c % 6, qq = ll >> 2, rr = ll & 3;
        #pragma unroll
        for (int jj = 0; jj < 4; ++jj)
            W2L[idx * 4 + jj] = W2g[(16 * s + qq) * H + 16 * jq + 4 * jj + rr];
    }
    for (int idx = tid; idx < 18 * 64; idx += BLOCK) {
        const int c = idx >> 6, ll = idx & 63;
        const int s = c / 6, jq = c % 6, qq = ll >> 2, rr = ll & 3;
        #pragma unroll
        for (int jj = 0; jj < 4; ++jj)
            W3L[idx * 4 + jj] = W3g[(16 * s + qq) * H + 16 * jq + 4 * jj + rr];
    }
    for (int idx = tid; idx < 96 * 12; idx += BLOCK) {
        const int n = idx / 12, k = idx % 12;
        W1L[idx] = (k < 9) ? W1g[n * D_INP + k] : 0.0f;
    }

    // ---- small persistent register state (biases direct from global) ----
    float bb1[2], bb2[2];
    #pragma unroll
    for (int i = 0; i < 2; ++i) {
        bb1[i] = b1g[l15 + 16 * (2 * h + i)];
        bb2[i] = b2g[16 * (2 * h + i) + q];
    }
    const float bb3 = b3g[16 * h + q];
    float m1[2] = {}, m2[2] = {}, m3 = 0.f;

    // x pointer for this lane's L1 batch; advanced one timestep per t.
    const float* xp = x + (size_t)(bgp + bL) * D_INP;
    float xr[D_INP];
    #pragma unroll
    for (int k = 0; k < D_INP; ++k) xr[k] = xp[k];

    unsigned char* s1b = (unsigned char*)&s1p[g][0][0];
    unsigned char* s2b = (unsigned char*)&s2p[g][0][0];
    // output pointers for (neuron 16h+q, batch bgp+r), advanced per t.
    float* ps = out + (size_t)(bgp + r) * H3 + 16 * h + q;
    float* pm = ps + (size_t)T_STEPS * BATCH * H3;

    __syncthreads();   // staging visible (full barrier, once)

    #pragma unroll 1
    for (int t = 0; t < T_STEPS; ++t) {
        // ---- layer 1: 9 -> 96. Role h: neurons [32h,32h+32), batch bL ----
        #pragma unroll
        for (int i = 0; i < 2; ++i) {
            const int n1 = l15 + 16 * (2 * h + i);
            const float4 wa = *(const float4*)&W1L[n1 * 12];
            const float4 wb = *(const float4*)&W1L[n1 * 12 + 4];
            const float  w8 = W1L[n1 * 12 + 8];
            const float q0 = __fmul_rn(wa.x, xr[0]);   // exact products
            const float q1 = __fmul_rn(wa.y, xr[1]);
            const float q2 = __fmul_rn(wa.z, xr[2]);
            const float q3 = __fmul_rn(wa.w, xr[3]);
            const float q4 = __fmul_rn(wb.x, xr[4]);
            const float q5 = __fmul_rn(wb.y, xr[5]);
            const float q6 = __fmul_rn(wb.z, xr[6]);
            const float q7 = __fmul_rn(wb.w, xr[7]);
            const float q8 = __fmul_rn(w8,   xr[8]);
            const float r0 = __fadd_rn(__fadd_rn(q8, q0), q4);   // tail-first
            const float r1 = __fadd_rn(q1, q5);
            const float r2 = __fadd_rn(q2, q6);
            const float r3 = __fadd_rn(q3, q7);
            const float s  = __fadd_rn(__fadd_rn(r0, r1), __fadd_rn(r2, r3));
            const float mn = lif_step(s, bb1[i], m1[i]);
            s1b[((n1 & 3) * 24 + (n1 >> 2)) * 4 + bL] =
                (mn > 1.0f) ? (unsigned char)1 : (unsigned char)0;
        }
        // register-prefetch x(t+1): stays in flight across the raw barriers.
        if (t + 1 < T_STEPS) {
            xp += (size_t)BATCH * D_INP;
            #pragma unroll
            for (int k = 0; k < D_INP; ++k) xr[k] = xp[k];
        }
        BLOCK_SYNC();   // BAR1: s1p visible

        // ---- layer 2: 96 -> 96. Role h: s = 2h, 2h+1 (acc[si][batch]) ----
        {
            float acc[2][4] = {};
            const unsigned* sb = &s1p[g][r][0];
            #pragma unroll
            for (int jq = 0; jq < 6; ++jq) {
                const uint4 sp = *(const uint4*)&sb[4 * jq];   // broadcast
                float sf[4][4];
                UNPACK4(sp.x, 0) UNPACK4(sp.y, 1) UNPACK4(sp.z, 2) UNPACK4(sp.w, 3)
                const float4 w0 = *(const float4*)&W2L[(((2 * h)     * 6 + jq) * 64 + l) * 4];
                const float4 w1 = *(const float4*)&W2L[(((2 * h + 1) * 6 + jq) * 64 + l) * 4];
                FMA16(acc[0], w0)
                FMA16(acc[1], w1)
            }
            #pragma unroll
            for (int si = 0; si < 2; ++si) {
                const float g0 = quad_red(acc[si][0]);   // (c0+c1)+(c2+c3)
                const float g1 = quad_red(acc[si][1]);
                const float g2 = quad_red(acc[si][2]);
                const float g3 = quad_red(acc[si][3]);
                const float sv = (r == 0) ? g0 : ((r == 1) ? g1 : ((r == 2) ? g2 : g3));
                const float mn = lif_step(sv, bb2[si], m2[si]);   // batch bgp+r
                const int n2 = 16 * (2 * h + si) + q;
                s2b[((n2 & 3) * 24 + (n2 >> 2)) * 4 + r] =
                    (mn > 1.0f) ? (unsigned char)1 : (unsigned char)0;
            }
        }
        BLOCK_SYNC();   // BAR2: s2p visible

        // ---- layer 3: 96 -> 48. Role h: s3 = h (neuron 16h+q) ----
        {
            float a3[4] = {};
            const unsigned* sb = &s2p[g][r][0];
            #pragma unroll
            for (int jq = 0; jq < 6; ++jq) {
                const uint4 sp = *(const uint4*)&sb[4 * jq];
                float sf[4][4];
                UNPACK4(sp.x, 0) UNPACK4(sp.y, 1) UNPACK4(sp.z, 2) UNPACK4(sp.w, 3)
                const float4 wv = *(const float4*)&W3L[((h * 6 + jq) * 64 + l) * 4];
                FMA16(a3, wv)
            }
            const float g0 = quad_red(a3[0]);
            const float g1 = quad_red(a3[1]);
            const float g2 = quad_red(a3[2]);
            const float g3 = quad_red(a3[3]);
            const float sv = (r == 0) ? g0 : ((r == 1) ? g1 : ((r == 2) ? g2 : g3));
            const float mn = lif_step(sv, bb3, m3);               // batch bgp+r
            *ps = (mn > 1.0f) ? 1.0f : 0.0f;
            *pm = mn;
            ps += (size_t)BATCH * H3;
            pm += (size_t)BATCH * H3;
        }
        // Next-t L1 writes s1p only after BAR2(t) (program order); next-t L2
        // writes s2p only after BAR1(t+1), which each wave reaches only after
        // its L3(t) reads drained. No extra fence needed.
    }
}

extern "C" void kernel_launch(void* const* d_in, const int* in_sizes, int n_in,
                              void* d_out, int out_size, void* d_ws, size_t ws_size,
                              hipStream_t stream)
{
    const float* x  = (const float*)d_in[0];
    const float* W1 = (const float*)d_in[1];
    const float* b1 = (const float*)d_in[2];
    const float* W2 = (const float*)d_in[3];
    const float* b2 = (const float*)d_in[4];
    const float* W3 = (const float*)d_in[5];
    const float* b3 = (const float*)d_in[6];
    float* out = (float*)d_out;

    snn_tri<<<dim3(NBLK), dim3(BLOCK), 0, stream>>>(
        x, W1, b1, W2, b2, W3, b3, out);
}

// Round 8
// 558.312 us; speedup vs baseline: 1.0974x; 1.0974x over previous
//
#include <hip/hip_runtime.h>

// DeepSNNController: 3-layer LIF SNN, T=100, B=4096, 9 -> 96 -> 96 -> 48.
//
// R16 "time-chunked" = R14 (wave-autonomous, zero barriers, BPW=2, 8 waves/CU)
// with TC=4 timesteps processed per weight sweep. R15 post-mortem: two ~60KB
// blocks never co-reside (occupancy 17.5% = 1 block) -> all barrier designs
// stuck ~500us; R14's barrier-free structure stands. R14's wall = LDS pipe:
// 432 weight ds_read_b128/CU/t (each wave re-reads all of W2+W3 per t for 2
// batches). KEY: the dot products c(t)=W*s(t) are state-independent (only
// the scalar LIF update is recurrent), so one weight read can feed fmas for
// FOUR timesteps: L1 x4 -> one W2 sweep (acc[tp][s][b]) -> LIF2 x4
// (t-sequential) -> one W3 sweep -> LIF3 x4. Weight reads/t drop 4x
// (432 -> 108 = 1.3k cyc); fma/cvt per t unchanged. Extra registers
// (acc 48 + w 48) are FREE: 8 waves/CU needs only 2 waves/SIMD = the
// VGPR<=256 tier (__launch_bounds__(512,2)).
//
// Exactness (absmax must stay 0): bit-identical to R14 (passed absmax=0).
// Same lane owns the same (neuron,batch) chains; per-accumulator fmaf chain
// is j-ascending per residue (jc outer asc, wA j=8jc..+3 then wB j=8jc+4..+7);
// combine (c0+c1)+(c2+c3) via quad-perm DPP exchange-adds; K=9 L1 tail-first
// r0=(q8+q0)+q4 verbatim; LIF pinned mn=((0.92*mp)+(dot+b))-reset, processed
// t-ascending (tp outer in every LIF loop). Products exact (spikes in {0,1}).
// Only the INTERLEAVING across independent chains changes -> same bits.
//
// Spike buffer: spk[TC][wave][4 r][24 j] ushorts (byte b = batch b, k=4j+r).
// s1 and s2 ALIAS the same buffer: s1 lifetime = L1-write..L2-read; s2 =
// LIF2-write..L3-read; disjoint within a chunk, same-wave, lgkm-fenced.
// LDS = 36864 (W2) + 18432 (W3) + 6144 (spk) = 61440 B. W1+biases in regs.
// Fences are lgkmcnt-only (never vmcnt): x loads / out stores stay in flight.

constexpr int T_STEPS = 100;
constexpr int BATCH   = 4096;
constexpr int D_INP   = 9;
constexpr int H       = 96;
constexpr int H3      = 48;
constexpr int WAVES   = 8;
constexpr int BPW     = 2;               // batches per wave
constexpr int NB      = WAVES * BPW;     // 16 batches per block
constexpr int BLOCK   = WAVES * 64;      // 512 threads
constexpr int NBLK    = BATCH / NB;      // 256 blocks = 1 per CU
constexpr int TC      = 4;               // timesteps per weight sweep

__device__ __forceinline__ float lif_step(float sum, float bias, float& m) {
    const float cur   = __fadd_rn(sum, bias);
    const float mp    = m;
    const float reset = (mp > 1.0f) ? 1.0f : 0.0f;
    const float mn    = __fsub_rn(__fadd_rn(__fmul_rn(0.92f, mp), cur), reset);
    m = mn;
    return mn;
}

#if defined(__has_builtin)
#if __has_builtin(__builtin_amdgcn_mov_dpp)
#define SNN_HAS_DPP 1
#endif
#endif

// Quad exchange-and-add. CTRL=0xB1: quad_perm [1,0,3,2] (xor 1);
// CTRL=0x4E: quad_perm [2,3,0,1] (xor 2).
template <int CTRL>
__device__ __forceinline__ float xadd(float c) {
#ifdef SNN_HAS_DPP
    const int o = __builtin_amdgcn_mov_dpp(__float_as_int(c), CTRL, 0xF, 0xF, false);
    return __fadd_rn(c, __int_as_float(o));
#else
    return __fadd_rn(c, __shfl_xor(c, (CTRL == 0xB1) ? 1 : 2, 64));
#endif
}

// lanes r=0..3 hold P7 residue partials c_r; returns (c0+c1)+(c2+c3) in ALL lanes.
__device__ __forceinline__ float quad_red(float c) {
    return xadd<0x4E>(xadd<0xB1>(c));
}

// dword = ushorts {j0, j0+1}: bytes [b0(j0), b1(j0), b0(j0+1), b1(j0+1)].
#define UNPACK2(dw, row)                                                      \
    sf[row][0]     = (float)( (dw)        & 255u);                            \
    sf[row][1]     = (float)(((dw) >> 8)  & 255u);                            \
    sf[(row)+1][0] = (float)(((dw) >> 16) & 255u);                            \
    sf[(row)+1][1] = (float)( (dw) >> 24);

// 8 fmas: weight component jj pairs with sf row jj (j ascending per chain).
#define FMA8(accv, wv, base)                                                  \
    accv[0] = fmaf(wv.x, sf[(base)+0][0], accv[0]);                           \
    accv[1] = fmaf(wv.x, sf[(base)+0][1], accv[1]);                           \
    accv[0] = fmaf(wv.y, sf[(base)+1][0], accv[0]);                           \
    accv[1] = fmaf(wv.y, sf[(base)+1][1], accv[1]);                           \
    accv[0] = fmaf(wv.z, sf[(base)+2][0], accv[0]);                           \
    accv[1] = fmaf(wv.z, sf[(base)+2][1], accv[1]);                           \
    accv[0] = fmaf(wv.w, sf[(base)+3][0], accv[0]);                           \
    accv[1] = fmaf(wv.w, sf[(base)+3][1], accv[1]);

// One timestep-slice of a weight sweep: unpack 8 j x 2 b spikes, advance NS
// neuron chains. All indices compile-time after inlining/unroll.
template <int NS>
__device__ __forceinline__ void sweep_tp(const uint4 spv,
                                         const float4* __restrict__ wA,
                                         const float4* __restrict__ wB,
                                         float (*__restrict__ acc)[2]) {
    float sf[8][2];
    UNPACK2(spv.x, 0) UNPACK2(spv.y, 2) UNPACK2(spv.z, 4) UNPACK2(spv.w, 6)
    #pragma unroll
    for (int s = 0; s < NS; ++s) { FMA8(acc[s], wA[s], 0) FMA8(acc[s], wB[s], 4) }
}

// LDS-only drain; VMEM (x loads, out stores) stays in flight on purpose.
#define FENCE_LGKM() asm volatile("s_waitcnt lgkmcnt(0)" ::: "memory")

__global__ __launch_bounds__(BLOCK, 2)
void snn_tc4(const float* __restrict__ x,
             const float* __restrict__ W1g, const float* __restrict__ b1g,
             const float* __restrict__ W2g, const float* __restrict__ b2g,
             const float* __restrict__ W3g, const float* __restrict__ b3g,
             float* __restrict__ out)
{
    // Chunk-major weights (R12/R13/R14-measured conflict-free): cell (c,l)=16B.
    __shared__ __align__(16) float          W2L[36 * 64 * 4];      // 36864 B
    __shared__ __align__(16) float          W3L[18 * 64 * 4];      // 18432 B
    // Spikes, batch-packed ushorts; s1 and s2 alias this buffer (see header).
    __shared__ __align__(16) unsigned short spk[TC][WAVES][4][24]; //  6144 B

    const int tid = threadIdx.x;
    const int w   = tid >> 6;     // wave 0..7
    const int l   = tid & 63;     // lane
    const int q   = l >> 2;       // quad 0..15
    const int r   = l & 3;        // residue lane
    const int r01 = r & 1;        // this lane's batch (0/1)
    const int bL  = l >> 5;       // L1 batch 0..1
    const int bg0 = blockIdx.x * NB + w * BPW;   // wave's batch base

    // ---- one-time weight staging (scattered; L2-cached) ----
    for (int idx = tid; idx < 36 * 64; idx += BLOCK) {
        const int c = idx >> 6, ll = idx & 63;
        const int s = c / 6, jq = c % 6, qq = ll >> 2, rr = ll & 3;
        #pragma unroll
        for (int jj = 0; jj < 4; ++jj)
            W2L[idx * 4 + jj] = W2g[(16 * s + qq) * H + 16 * jq + 4 * jj + rr];
    }
    for (int idx = tid; idx < 18 * 64; idx += BLOCK) {
        const int c = idx >> 6, ll = idx & 63;
        const int s = c / 6, jq = c % 6, qq = ll >> 2, rr = ll & 3;
        #pragma unroll
        for (int jj = 0; jj < 4; ++jj)
            W3L[idx * 4 + jj] = W3g[(16 * s + qq) * H + 16 * jq + 4 * jj + rr];
    }

    // ---- persistent register state: W1 + all biases + membranes ----
    float w1r[3][D_INP], bb1[3];
    #pragma unroll
    for (int i = 0; i < 3; ++i) {
        const int n1 = (l & 31) + 32 * i;
        #pragma unroll
        for (int k = 0; k < D_INP; ++k) w1r[i][k] = W1g[n1 * D_INP + k];
        bb1[i] = b1g[n1];
    }
    float bb2[6], bb3[3];
    #pragma unroll
    for (int s = 0; s < 6; ++s) bb2[s] = b2g[16 * s + q];
    #pragma unroll
    for (int s = 0; s < 3; ++s) bb3[s] = b3g[16 * s + q];
    float m1[3] = {}, m2[6] = {}, m3[3] = {};

    float* out_spk = out;
    float* out_mem = out + (size_t)T_STEPS * BATCH * H3;

    __syncthreads();   // THE ONLY BLOCK BARRIER (weights visible)

    #pragma unroll 1
    for (int tc = 0; tc < T_STEPS; tc += TC) {
        // ---- x for 4 timesteps (broadcast loads; vmcnt only at first use) ----
        float xr[TC][D_INP];
        const float* xp = x + ((size_t)tc * BATCH + bg0 + bL) * D_INP;
        #pragma unroll
        for (int tp = 0; tp < TC; ++tp) {
            #pragma unroll
            for (int k = 0; k < D_INP; ++k)
                xr[tp][k] = xp[(size_t)tp * BATCH * D_INP + k];
        }

        // ---- layer 1 x4: P7 order verbatim, t-ascending (m1 recurrence) ----
        #pragma unroll
        for (int tp = 0; tp < TC; ++tp) {
            unsigned char* s1b = (unsigned char*)&spk[tp][w][0][0];
            #pragma unroll
            for (int i = 0; i < 3; ++i) {
                const int n1 = (l & 31) + 32 * i;
                const float q0 = __fmul_rn(w1r[i][0], xr[tp][0]);   // exact
                const float q1 = __fmul_rn(w1r[i][1], xr[tp][1]);
                const float q2 = __fmul_rn(w1r[i][2], xr[tp][2]);
                const float q3 = __fmul_rn(w1r[i][3], xr[tp][3]);
                const float q4 = __fmul_rn(w1r[i][4], xr[tp][4]);
                const float q5 = __fmul_rn(w1r[i][5], xr[tp][5]);
                const float q6 = __fmul_rn(w1r[i][6], xr[tp][6]);
                const float q7 = __fmul_rn(w1r[i][7], xr[tp][7]);
                const float q8 = __fmul_rn(w1r[i][8], xr[tp][8]);
                const float r0 = __fadd_rn(__fadd_rn(q8, q0), q4);  // tail-first
                const float r1 = __fadd_rn(q1, q5);
                const float r2 = __fadd_rn(q2, q6);
                const float r3 = __fadd_rn(q3, q7);
                const float s  = __fadd_rn(__fadd_rn(r0, r1), __fadd_rn(r2, r3));
                const float mn = lif_step(s, bb1[i], m1[i]);
                s1b[((n1 & 3) * 24 + (n1 >> 2)) * 2 + bL] =
                    (mn > 1.0f) ? (unsigned char)1 : (unsigned char)0;
            }
        }
        FENCE_LGKM();   // s1 writes land before the sweep reads

        // ---- ONE W2 sweep feeds all 4 timesteps ----
        float acc[TC][6][2] = {};
        #pragma unroll
        for (int jc = 0; jc < 3; ++jc) {
            const uint4 sp0 = *(const uint4*)&spk[0][w][r][8 * jc];
            const uint4 sp1 = *(const uint4*)&spk[1][w][r][8 * jc];
            const uint4 sp2 = *(const uint4*)&spk[2][w][r][8 * jc];
            const uint4 sp3 = *(const uint4*)&spk[3][w][r][8 * jc];
            float4 wA[6], wB[6];
            #pragma unroll
            for (int s = 0; s < 6; ++s) {
                wA[s] = *(const float4*)&W2L[((s * 6 + 2 * jc)     * 64 + l) * 4];
                wB[s] = *(const float4*)&W2L[((s * 6 + 2 * jc + 1) * 64 + l) * 4];
            }
            sweep_tp<6>(sp0, wA, wB, acc[0]);
            sweep_tp<6>(sp1, wA, wB, acc[1]);
            sweep_tp<6>(sp2, wA, wB, acc[2]);
            sweep_tp<6>(sp3, wA, wB, acc[3]);
        }
        FENCE_LGKM();   // WAR: all s1 reads done before s2 overwrites the buffer

        // ---- LIF2 x4 (t-ascending per m2[s] chain) + s2 writes ----
        #pragma unroll
        for (int tp = 0; tp < TC; ++tp) {
            unsigned char* s2b = (unsigned char*)&spk[tp][w][0][0];
            #pragma unroll
            for (int s = 0; s < 6; ++s) {
                const float g0 = quad_red(acc[tp][s][0]);   // (c0+c1)+(c2+c3)
                const float g1 = quad_red(acc[tp][s][1]);
                const float sv = r01 ? g1 : g0;
                const float mn = lif_step(sv, bb2[s], m2[s]);   // batch r01
                if (r < 2) {
                    const int n2 = 16 * s + q;
                    s2b[((n2 & 3) * 24 + (n2 >> 2)) * 2 + r] =
                        (mn > 1.0f) ? (unsigned char)1 : (unsigned char)0;
                }
            }
        }
        FENCE_LGKM();   // s2 writes land before the L3 sweep reads

        // ---- ONE W3 sweep feeds all 4 timesteps ----
        float a3[TC][3][2] = {};
        #pragma unroll
        for (int jc = 0; jc < 3; ++jc) {
            const uint4 sp0 = *(const uint4*)&spk[0][w][r][8 * jc];
            const uint4 sp1 = *(const uint4*)&spk[1][w][r][8 * jc];
            const uint4 sp2 = *(const uint4*)&spk[2][w][r][8 * jc];
            const uint4 sp3 = *(const uint4*)&spk[3][w][r][8 * jc];
            float4 wA[3], wB[3];
            #pragma unroll
            for (int s = 0; s < 3; ++s) {
                wA[s] = *(const float4*)&W3L[((s * 6 + 2 * jc)     * 64 + l) * 4];
                wB[s] = *(const float4*)&W3L[((s * 6 + 2 * jc + 1) * 64 + l) * 4];
            }
            sweep_tp<3>(sp0, wA, wB, a3[0]);
            sweep_tp<3>(sp1, wA, wB, a3[1]);
            sweep_tp<3>(sp2, wA, wB, a3[2]);
            sweep_tp<3>(sp3, wA, wB, a3[3]);
        }

        // ---- LIF3 x4 + stores (t-ascending per m3[s] chain) ----
        #pragma unroll
        for (int tp = 0; tp < TC; ++tp) {
            #pragma unroll
            for (int s = 0; s < 3; ++s) {
                const float g0 = quad_red(a3[tp][s][0]);
                const float g1 = quad_red(a3[tp][s][1]);
                const float sv = r01 ? g1 : g0;
                const float mn = lif_step(sv, bb3[s], m3[s]);   // batch r01
                if (r < 2) {
                    const size_t ob =
                        ((size_t)(tc + tp) * BATCH + bg0 + r) * H3 + 16 * s + q;
                    out_spk[ob] = (mn > 1.0f) ? 1.0f : 0.0f;
                    out_mem[ob] = mn;
                }
            }
        }
        FENCE_LGKM();   // WAR: L3's s2 reads done before next chunk's L1 writes
    }
}

extern "C" void kernel_launch(void* const* d_in, const int* in_sizes, int n_in,
                              void* d_out, int out_size, void* d_ws, size_t ws_size,
                              hipStream_t stream)
{
    const float* x  = (const float*)d_in[0];
    const float* W1 = (const float*)d_in[1];
    const float* b1 = (const float*)d_in[2];
    const float* W2 = (const float*)d_in[3];
    const float* b2 = (const float*)d_in[4];
    const float* W3 = (const float*)d_in[5];
    const float* b3 = (const float*)d_in[6];
    float* out = (float*)d_out;

    snn_tc4<<<dim3(NBLK), dim3(BLOCK), 0, stream>>>(
        x, W1, b1, W2, b2, W3, b3, out);
}

// Round 9
// 402.226 us; speedup vs baseline: 1.5233x; 1.3881x over previous
//
#include <hip/hip_runtime.h>

// DeepSNNController: 3-layer LIF SNN, T=100, B=4096, 9 -> 96 -> 96 -> 48.
//
// R17 = R16's time-chunked schedule (correctness-verified, absmax=0) resized
// to the session's measured allocator envelope. R16 post-mortem: TC=4's
// working set (acc48 + w48 + sf64 + w1r27 + xr36) blew the ~120-VGPR usable
// budget -> 142MB scratch FETCH, 27MB scratch WRITE, 445us. Allocator law
// (R10/R11/R16): >~120 live VGPRs/lane spills; no attribute overrides it.
// Fixes, keeping the verified schedule:
//   * TC=2 (weight reads halve vs R14: 432 -> 216 b128/CU/t).
//   * W1 back to LDS (R14's verified path): -27 VGPR; xr 36 -> 18.
//   * Sweep staging: per jc load 2 spike uint4s, unpack BOTH timesteps
//     (sf=32), then s-halves of 3 neurons (weight tile 24, not 48).
//   Peak live ~ 40 persistent + 24 acc + 32 sf + 24 w ~ 120 < 128.
//
// Exactness (absmax must stay 0): bit-identical chains to R14/R16 (both
// passed absmax=0). Per accumulator (tp, s, b): fmaf chain j-ascending
// (jc outer asc; within jc: wA j=8jc..+3 then wB j=8jc+4..+7); only the
// interleave ACROSS independent chains changes (sh/si/tp loop order), which
// cannot change any chain's bits. Combine (c0+c1)+(c2+c3) via quad-perm DPP
// exchange-adds; K=9 L1 tail-first r0=(q8+q0)+q4 verbatim; LIF pinned
// mn=((0.92*mp)+(dot+b))-reset, t-ascending per membrane chain. Products
// exact (spikes in {0,1}). Spike buffer s1/s2 aliasing scheme = R16's
// (verified); lifetimes disjoint per chunk, lgkm-fenced, same-wave.
//
// Structure: wave-autonomous (zero barriers in t-loop), 8 waves x 2 batches,
// grid 256 = 1 block/CU = 2 waves/SIMD. Weights chunk-major 16B cells
// (measured conflict-free). Fences lgkmcnt-only; x loads / out stores stay
// in flight across phases.

constexpr int T_STEPS = 100;
constexpr int BATCH   = 4096;
constexpr int D_INP   = 9;
constexpr int H       = 96;
constexpr int H3      = 48;
constexpr int WAVES   = 8;
constexpr int BPW     = 2;               // batches per wave
constexpr int NB      = WAVES * BPW;     // 16 batches per block
constexpr int BLOCK   = WAVES * 64;      // 512 threads
constexpr int NBLK    = BATCH / NB;      // 256 blocks = 1 per CU
constexpr int TC      = 2;               // timesteps per weight sweep

__device__ __forceinline__ float lif_step(float sum, float bias, float& m) {
    const float cur   = __fadd_rn(sum, bias);
    const float mp    = m;
    const float reset = (mp > 1.0f) ? 1.0f : 0.0f;
    const float mn    = __fsub_rn(__fadd_rn(__fmul_rn(0.92f, mp), cur), reset);
    m = mn;
    return mn;
}

#if defined(__has_builtin)
#if __has_builtin(__builtin_amdgcn_mov_dpp)
#define SNN_HAS_DPP 1
#endif
#endif

// Quad exchange-and-add. CTRL=0xB1: quad_perm [1,0,3,2] (xor 1);
// CTRL=0x4E: quad_perm [2,3,0,1] (xor 2).
template <int CTRL>
__device__ __forceinline__ float xadd(float c) {
#ifdef SNN_HAS_DPP
    const int o = __builtin_amdgcn_mov_dpp(__float_as_int(c), CTRL, 0xF, 0xF, false);
    return __fadd_rn(c, __int_as_float(o));
#else
    return __fadd_rn(c, __shfl_xor(c, (CTRL == 0xB1) ? 1 : 2, 64));
#endif
}

// lanes r=0..3 hold P7 residue partials c_r; returns (c0+c1)+(c2+c3) in ALL lanes.
__device__ __forceinline__ float quad_red(float c) {
    return xadd<0x4E>(xadd<0xB1>(c));
}

// dword = ushorts {j0, j0+1}: bytes [b0(j0), b1(j0), b0(j0+1), b1(j0+1)].
// All sf indices compile-time (rule: no runtime-indexed register arrays).
#define UNPACK2S(dw, row, sfarr)                                              \
    sfarr[row][0]     = (float)( (dw)        & 255u);                         \
    sfarr[row][1]     = (float)(((dw) >> 8)  & 255u);                         \
    sfarr[(row)+1][0] = (float)(((dw) >> 16) & 255u);                         \
    sfarr[(row)+1][1] = (float)( (dw) >> 24);

// 8 fmas: weight component jj pairs with sf row jj (j ascending per chain).
#define FMA8S(accv, wv, sfarr, base)                                          \
    accv[0] = fmaf(wv.x, sfarr[(base)+0][0], accv[0]);                        \
    accv[1] = fmaf(wv.x, sfarr[(base)+0][1], accv[1]);                        \
    accv[0] = fmaf(wv.y, sfarr[(base)+1][0], accv[0]);                        \
    accv[1] = fmaf(wv.y, sfarr[(base)+1][1], accv[1]);                        \
    accv[0] = fmaf(wv.z, sfarr[(base)+2][0], accv[0]);                        \
    accv[1] = fmaf(wv.z, sfarr[(base)+2][1], accv[1]);                        \
    accv[0] = fmaf(wv.w, sfarr[(base)+3][0], accv[0]);                        \
    accv[1] = fmaf(wv.w, sfarr[(base)+3][1], accv[1]);

// LDS-only drain; VMEM (x loads, out stores) stays in flight on purpose.
#define FENCE_LGKM() asm volatile("s_waitcnt lgkmcnt(0)" ::: "memory")

__global__ __launch_bounds__(BLOCK, 2)
void snn_tc2(const float* __restrict__ x,
             const float* __restrict__ W1g, const float* __restrict__ b1g,
             const float* __restrict__ W2g, const float* __restrict__ b2g,
             const float* __restrict__ W3g, const float* __restrict__ b3g,
             float* __restrict__ out)
{
    // Chunk-major weights (measured conflict-free): cell (c,l) = 16 B.
    __shared__ __align__(16) float          W2L[36 * 64 * 4];      // 36864 B
    __shared__ __align__(16) float          W3L[18 * 64 * 4];      // 18432 B
    __shared__ __align__(16) float          W1L[96 * 12];          //  4608 B
    // Spikes, batch-packed ushorts; s1/s2 alias this buffer (R16-verified).
    __shared__ __align__(16) unsigned short spk[TC][WAVES][4][24]; //  3072 B
    // total 62,976 B -> 1 block/CU, 8 waves/CU = 2/SIMD.

    const int tid = threadIdx.x;
    const int w   = tid >> 6;     // wave 0..7
    const int l   = tid & 63;     // lane
    const int q   = l >> 2;       // quad 0..15
    const int r   = l & 3;        // residue lane
    const int r01 = r & 1;        // this lane's batch (0/1)
    const int bL  = l >> 5;       // L1 batch 0..1
    const int bg0 = blockIdx.x * NB + w * BPW;   // wave's batch base

    // ---- one-time weight staging (scattered; L2-cached) ----
    for (int idx = tid; idx < 36 * 64; idx += BLOCK) {
        const int c = idx >> 6, ll = idx & 63;
        const int s = c / 6, jq = c % 6, qq = ll >> 2, rr = ll & 3;
        #pragma unroll
        for (int jj = 0; jj < 4; ++jj)
            W2L[idx * 4 + jj] = W2g[(16 * s + qq) * H + 16 * jq + 4 * jj + rr];
    }
    for (int idx = tid; idx < 18 * 64; idx += BLOCK) {
        const int c = idx >> 6, ll = idx & 63;
        const int s = c / 6, jq = c % 6, qq = ll >> 2, rr = ll & 3;
        #pragma unroll
        for (int jj = 0; jj < 4; ++jj)
            W3L[idx * 4 + jj] = W3g[(16 * s + qq) * H + 16 * jq + 4 * jj + rr];
    }
    for (int idx = tid; idx < 96 * 12; idx += BLOCK) {
        const int n = idx / 12, k = idx % 12;
        W1L[idx] = (k < 9) ? W1g[n * D_INP + k] : 0.0f;
    }

    // ---- persistent register state: biases + membranes only ----
    float bb1[3], bb2[6], bb3[3];
    #pragma unroll
    for (int i = 0; i < 3; ++i) bb1[i] = b1g[(l & 31) + 32 * i];
    #pragma unroll
    for (int s = 0; s < 6; ++s) bb2[s] = b2g[16 * s + q];
    #pragma unroll
    for (int s = 0; s < 3; ++s) bb3[s] = b3g[16 * s + q];
    float m1[3] = {}, m2[6] = {}, m3[3] = {};

    float* out_spk = out;
    float* out_mem = out + (size_t)T_STEPS * BATCH * H3;

    __syncthreads();   // THE ONLY BLOCK BARRIER (weights visible)

    #pragma unroll 1
    for (int tc = 0; tc < T_STEPS; tc += TC) {
        // ---- x for 2 timesteps (broadcast loads) ----
        float xr[TC][D_INP];
        const float* xp = x + ((size_t)tc * BATCH + bg0 + bL) * D_INP;
        #pragma unroll
        for (int tp = 0; tp < TC; ++tp) {
            #pragma unroll
            for (int k = 0; k < D_INP; ++k)
                xr[tp][k] = xp[(size_t)tp * BATCH * D_INP + k];
        }

        // ---- layer 1 x2: P7 order verbatim, t-ascending (m1 recurrence) ----
        #pragma unroll
        for (int tp = 0; tp < TC; ++tp) {
            unsigned char* s1b = (unsigned char*)&spk[tp][w][0][0];
            #pragma unroll
            for (int i = 0; i < 3; ++i) {
                const int n1 = (l & 31) + 32 * i;
                const float4 wa = *(const float4*)&W1L[n1 * 12];
                const float4 wb = *(const float4*)&W1L[n1 * 12 + 4];
                const float  w8 = W1L[n1 * 12 + 8];
                const float q0 = __fmul_rn(wa.x, xr[tp][0]);   // exact
                const float q1 = __fmul_rn(wa.y, xr[tp][1]);
                const float q2 = __fmul_rn(wa.z, xr[tp][2]);
                const float q3 = __fmul_rn(wa.w, xr[tp][3]);
                const float q4 = __fmul_rn(wb.x, xr[tp][4]);
                const float q5 = __fmul_rn(wb.y, xr[tp][5]);
                const float q6 = __fmul_rn(wb.z, xr[tp][6]);
                const float q7 = __fmul_rn(wb.w, xr[tp][7]);
                const float q8 = __fmul_rn(w8,   xr[tp][8]);
                const float r0 = __fadd_rn(__fadd_rn(q8, q0), q4);  // tail-first
                const float r1 = __fadd_rn(q1, q5);
                const float r2 = __fadd_rn(q2, q6);
                const float r3 = __fadd_rn(q3, q7);
                const float s  = __fadd_rn(__fadd_rn(r0, r1), __fadd_rn(r2, r3));
                const float mn = lif_step(s, bb1[i], m1[i]);
                s1b[((n1 & 3) * 24 + (n1 >> 2)) * 2 + bL] =
                    (mn > 1.0f) ? (unsigned char)1 : (unsigned char)0;
            }
        }
        FENCE_LGKM();   // s1 writes land before the sweep reads

        // ---- ONE W2 sweep feeds both timesteps ----
        float acc[TC][6][2] = {};
        #pragma unroll
        for (int jc = 0; jc < 3; ++jc) {
            const uint4 sp0 = *(const uint4*)&spk[0][w][r][8 * jc];
            const uint4 sp1 = *(const uint4*)&spk[1][w][r][8 * jc];
            float sf0[8][2], sf1[8][2];
            UNPACK2S(sp0.x, 0, sf0) UNPACK2S(sp0.y, 2, sf0)
            UNPACK2S(sp0.z, 4, sf0) UNPACK2S(sp0.w, 6, sf0)
            UNPACK2S(sp1.x, 0, sf1) UNPACK2S(sp1.y, 2, sf1)
            UNPACK2S(sp1.z, 4, sf1) UNPACK2S(sp1.w, 6, sf1)
            #pragma unroll
            for (int sh = 0; sh < 2; ++sh) {          // s-halves {0..2},{3..5}
                float4 wA[3], wB[3];
                #pragma unroll
                for (int si = 0; si < 3; ++si) {
                    const int s = 3 * sh + si;
                    wA[si] = *(const float4*)&W2L[((s * 6 + 2 * jc)     * 64 + l) * 4];
                    wB[si] = *(const float4*)&W2L[((s * 6 + 2 * jc + 1) * 64 + l) * 4];
                }
                #pragma unroll
                for (int si = 0; si < 3; ++si) {
                    FMA8S(acc[0][3 * sh + si], wA[si], sf0, 0)
                    FMA8S(acc[0][3 * sh + si], wB[si], sf0, 4)
                    FMA8S(acc[1][3 * sh + si], wA[si], sf1, 0)
                    FMA8S(acc[1][3 * sh + si], wB[si], sf1, 4)
                }
            }
        }
        FENCE_LGKM();   // WAR: all s1 reads done before s2 overwrites buffer

        // ---- LIF2 x2 (t-ascending per m2[s] chain) + s2 writes ----
        #pragma unroll
        for (int tp = 0; tp < TC; ++tp) {
            unsigned char* s2b = (unsigned char*)&spk[tp][w][0][0];
            #pragma unroll
            for (int s = 0; s < 6; ++s) {
                const float g0 = quad_red(acc[tp][s][0]);   // (c0+c1)+(c2+c3)
                const float g1 = quad_red(acc[tp][s][1]);
                const float sv = r01 ? g1 : g0;
                const float mn = lif_step(sv, bb2[s], m2[s]);   // batch r01
                if (r < 2) {
                    const int n2 = 16 * s + q;
                    s2b[((n2 & 3) * 24 + (n2 >> 2)) * 2 + r] =
                        (mn > 1.0f) ? (unsigned char)1 : (unsigned char)0;
                }
            }
        }
        FENCE_LGKM();   // s2 writes land before the L3 sweep reads

        // ---- ONE W3 sweep feeds both timesteps ----
        float a3[TC][3][2] = {};
        #pragma unroll
        for (int jc = 0; jc < 3; ++jc) {
            const uint4 sp0 = *(const uint4*)&spk[0][w][r][8 * jc];
            const uint4 sp1 = *(const uint4*)&spk[1][w][r][8 * jc];
            float sf0[8][2], sf1[8][2];
            UNPACK2S(sp0.x, 0, sf0) UNPACK2S(sp0.y, 2, sf0)
            UNPACK2S(sp0.z, 4, sf0) UNPACK2S(sp0.w, 6, sf0)
            UNPACK2S(sp1.x, 0, sf1) UNPACK2S(sp1.y, 2, sf1)
            UNPACK2S(sp1.z, 4, sf1) UNPACK2S(sp1.w, 6, sf1)
            float4 wA[3], wB[3];
            #pragma unroll
            for (int s = 0; s < 3; ++s) {
                wA[s] = *(const float4*)&W3L[((s * 6 + 2 * jc)     * 64 + l) * 4];
                wB[s] = *(const float4*)&W3L[((s * 6 + 2 * jc + 1) * 64 + l) * 4];
            }
            #pragma unroll
            for (int s = 0; s < 3; ++s) {
                FMA8S(a3[0][s], wA[s], sf0, 0)
                FMA8S(a3[0][s], wB[s], sf0, 4)
                FMA8S(a3[1][s], wA[s], sf1, 0)
                FMA8S(a3[1][s], wB[s], sf1, 4)
            }
        }

        // ---- LIF3 x2 + stores (t-ascending per m3[s] chain) ----
        #pragma unroll
        for (int tp = 0; tp < TC; ++tp) {
            #pragma unroll
            for (int s = 0; s < 3; ++s) {
                const float g0 = quad_red(a3[tp][s][0]);
                const float g1 = quad_red(a3[tp][s][1]);
                const float sv = r01 ? g1 : g0;
                const float mn = lif_step(sv, bb3[s], m3[s]);   // batch r01
                if (r < 2) {
                    const size_t ob =
                        ((size_t)(tc + tp) * BATCH + bg0 + r) * H3 + 16 * s + q;
                    out_spk[ob] = (mn > 1.0f) ? 1.0f : 0.0f;
                    out_mem[ob] = mn;
                }
            }
        }
        FENCE_LGKM();   // WAR: L3's s2 reads done before next chunk's L1 writes
    }
}

extern "C" void kernel_launch(void* const* d_in, const int* in_sizes, int n_in,
                              void* d_out, int out_size, void* d_ws, size_t ws_size,
                              hipStream_t stream)
{
    const float* x  = (const float*)d_in[0];
    const float* W1 = (const float*)d_in[1];
    const float* b1 = (const float*)d_in[2];
    const float* W2 = (const float*)d_in[3];
    const float* b2 = (const float*)d_in[4];
    const float* W3 = (const float*)d_in[5];
    const float* b3 = (const float*)d_in[6];
    float* out = (float*)d_out;

    snn_tc2<<<dim3(NBLK), dim3(BLOCK), 0, stream>>>(
        x, W1, b1, W2, b2, W3, b3, out);
}